// Round 4
// baseline (2302.208 us; speedup 1.0000x reference)
//
#include <hip/hip_runtime.h>
#include <hip/hip_bf16.h>

// B=256, T=2048, I=H=256, O=16. fp32 in/out. xp kept f16 as [b][t][n].

typedef _Float16 f16;
typedef _Float16 h8_t __attribute__((ext_vector_type(8)));
typedef _Float16 h2_t __attribute__((ext_vector_type(2)));
typedef float    f4_t __attribute__((ext_vector_type(4)));

__device__ __forceinline__ float fdot2u(unsigned w, unsigned h, float c) {
  return __builtin_amdgcn_fdot2(__builtin_bit_cast(h2_t, w),
                                __builtin_bit_cast(h2_t, h), c, false);
}
__device__ __forceinline__ unsigned pkrtz(float a, float b) {
  return __builtin_bit_cast(unsigned, __builtin_amdgcn_cvt_pkrtz(a, b));
}
// Rematerialization barrier: after this, the compiler cannot re-load v from
// memory — it must keep the (possibly "modified") value register-resident.
__device__ __forceinline__ void pin4(uint4& v) {
  asm volatile("" : "+v"(v.x), "+v"(v.y), "+v"(v.z), "+v"(v.w));
}

// ---------------------------------------------------------------------------
// prep: Wfrag = W_ih in MFMA B-fragment order; Wc2 = W_hh packed pairs in
// rnn per-lane granule order (wave w owns k-slice [64w,64w+64)).
// ---------------------------------------------------------------------------
__global__ __launch_bounds__(256) void prep_kernel(const float* __restrict__ Wih,
                                                   const float* __restrict__ Whh,
                                                   uint4* __restrict__ Wfrag,
                                                   uint4* __restrict__ Wc2) {
  int idx = blockIdx.x * 256 + threadIdx.x;   // 0..16383
  int e = idx & 8191;
  int gi = e >> 8;          // 0..31
  int lg = e & 255;         // w*64+l
  int w = lg >> 6, l = lg & 63;
  unsigned r[4];
  if (idx < 8192) {
    int nt = gi >> 3, ks = gi & 7;
    int n = w * 64 + nt * 16 + (l & 15);
    int k0 = ks * 32 + (l >> 4) * 8;
#pragma unroll
    for (int c = 0; c < 4; ++c)
      r[c] = pkrtz(Wih[(k0 + 2 * c) * 256 + n], Wih[(k0 + 2 * c + 1) * 256 + n]);
    Wfrag[gi * 256 + lg] = make_uint4(r[0], r[1], r[2], r[3]);
  } else {
    int oi = gi >> 3, q2 = gi & 7;
    int j = l + 64 * oi;
    int kb = 64 * w + 8 * q2;
#pragma unroll
    for (int c = 0; c < 4; ++c)
      r[c] = pkrtz(Whh[(kb + 2 * c) * 256 + j], Whh[(kb + 2 * c + 1) * 256 + j]);
    Wc2[gi * 256 + lg] = make_uint4(r[0], r[1], r[2], r[3]);
  }
}

// ---------------------------------------------------------------------------
// GEMM: block = (batch b, range of 64-step t-tiles). x tile contiguous 64KB
// fp32 -> f16 -> padded LDS. W frags pinned in VGPRs, reused across tiles.
// ---------------------------------------------------------------------------
__global__ __launch_bounds__(256, 2) void gemm_kernel(const float* __restrict__ x,
                                                      const uint4* __restrict__ Wfrag,
                                                      f16* __restrict__ xp,
                                                      int t0, int CT,
                                                      int tpb, int bpb) {
  __shared__ f16 As[64][264];                 // +8 f16 pad per row
  int tid = threadIdx.x;
  int wave = tid >> 6, l = tid & 63, l15 = l & 15, q = l >> 4;

  uint4 bf[4][8];
#pragma unroll
  for (int nt = 0; nt < 4; ++nt)
#pragma unroll
    for (int ks = 0; ks < 8; ++ks)
      bf[nt][ks] = Wfrag[(nt * 8 + ks) * 256 + tid];
#pragma unroll
  for (int nt = 0; nt < 4; ++nt)
#pragma unroll
    for (int ks = 0; ks < 8; ++ks) pin4(bf[nt][ks]);

  int b = blockIdx.x / bpb;
  int tb = blockIdx.x - b * bpb;
  f16* xpo = xp + (size_t)b * CT * 256;       // xp[b][tl][n]

  for (int sub = 0; sub < tpb; ++sub) {
    int tl0 = (tb * tpb + sub) * 64;
    const uint4* xsrc = (const uint4*)(x + ((size_t)b * 2048 + t0 + tl0) * 256);
    __syncthreads();                          // As reuse guard
#pragma unroll 4
    for (int i = 0; i < 16; ++i) {            // 64KB tile: 16 uint4/thread
      int fi = i * 256 + tid;
      float4 f = __builtin_bit_cast(float4, xsrc[fi]);
      int row = fi >> 6;
      int k = (fi & 63) * 4;
      uint2 pv; pv.x = pkrtz(f.x, f.y); pv.y = pkrtz(f.z, f.w);
      *(uint2*)&As[row][k] = pv;
    }
    __syncthreads();

    for (int mt = 0; mt < 4; ++mt) {
      uint4 af[8];
#pragma unroll
      for (int ks = 0; ks < 8; ++ks)
        af[ks] = *(const uint4*)&As[mt * 16 + l15][ks * 32 + q * 8];
      f4_t acc[4];
#pragma unroll
      for (int nt = 0; nt < 4; ++nt) acc[nt] = (f4_t){0.f, 0.f, 0.f, 0.f};
#pragma unroll
      for (int ks = 0; ks < 8; ++ks) {
        h8_t a = __builtin_bit_cast(h8_t, af[ks]);
#pragma unroll
        for (int nt = 0; nt < 4; ++nt)
          acc[nt] = __builtin_amdgcn_mfma_f32_16x16x32_f16(
              a, __builtin_bit_cast(h8_t, bf[nt][ks]), acc[nt], 0, 0, 0);
      }
#pragma unroll
      for (int nt = 0; nt < 4; ++nt) {
        int n = wave * 64 + nt * 16 + l15;
#pragma unroll
        for (int r = 0; r < 4; ++r)
          xpo[(size_t)(tl0 + mt * 16 + q * 4 + r) * 256 + n] = (f16)acc[nt][r];
      }
    }
  }
}

// ---------------------------------------------------------------------------
// RNN: 256 blocks x 256 threads, K-split by wave (wave w: k in [64w,64w+64)
// for all 256 outputs, 4 outputs/lane). Weights PINNED in 128 VGPRs.
// hbuf is wave-private => no barrier; prt double-buffered => 1 barrier/step.
// ---------------------------------------------------------------------------
__global__ __launch_bounds__(256, 1) void rnn_kernel(const f16* __restrict__ xp,
                                                     const uint4* __restrict__ Wc2,
                                                     const float* __restrict__ b_h,
                                                     const float* __restrict__ fc_w,
                                                     const float* __restrict__ fc_b,
                                                     float* __restrict__ hstate,
                                                     float* __restrict__ out,
                                                     int t0, int CT) {
  __shared__ f16 hbuf[256];
  __shared__ float prt[2][4][256];
  __shared__ float hf[256];
  __shared__ float prt2[16][16];

  int b = blockIdx.x, tid = threadIdx.x;
  int w = tid >> 6, l = tid & 63;

  uint4 wv[32];                                // 128 VGPRs of W_hh granules
#pragma unroll
  for (int g = 0; g < 32; ++g) wv[g] = Wc2[g * 256 + tid];
#pragma unroll
  for (int g = 0; g < 32; ++g) pin4(wv[g]);

  float hcur = (t0 == 0) ? 0.0f : hstate[b * 256 + tid];
  hbuf[tid] = (f16)hcur;
  float bhv = b_h[tid];

  const f16* xpb = xp + (size_t)b * CT * 256 + tid;
  f16 xq[4];                                   // 4-step-deep x prefetch
#pragma unroll
  for (int i = 0; i < 4; ++i) {
    int p = (i < CT) ? i : CT - 1;
    xq[i] = xpb[(size_t)p * 256];
  }

  for (int tt = 0; tt < CT; ++tt) {
    float xv = (float)xq[tt & 3];
    int pf = (tt + 4 < CT) ? tt + 4 : CT - 1;
    xq[tt & 3] = xpb[(size_t)pf * 256];

    const uint4* hb = (const uint4*)&hbuf[w * 64];   // wave-private slice
    uint4 hh[8];
#pragma unroll
    for (int q2 = 0; q2 < 8; ++q2) hh[q2] = hb[q2];  // broadcast reads

    float s[4];
#pragma unroll
    for (int oi = 0; oi < 4; ++oi) {
      float a0 = 0.f, a1 = 0.f;
#pragma unroll
      for (int q2 = 0; q2 < 8; ++q2) {
        uint4 wq = wv[oi * 8 + q2];
        a0 = fdot2u(wq.x, hh[q2].x, a0);
        a1 = fdot2u(wq.y, hh[q2].y, a1);
        a0 = fdot2u(wq.z, hh[q2].z, a0);
        a1 = fdot2u(wq.w, hh[q2].w, a1);
      }
      s[oi] = a0 + a1;
    }
    float* pw = prt[tt & 1][w];
#pragma unroll
    for (int oi = 0; oi < 4; ++oi) pw[l + 64 * oi] = s[oi];
    __syncthreads();                           // the ONLY barrier per step

    const float (*pr)[256] = prt[tt & 1];
    float z = pr[0][tid] + pr[1][tid] + pr[2][tid] + pr[3][tid] + xv + bhv;
    float e = __expf(2.0f * z);
    hcur = 1.0f - 2.0f * __builtin_amdgcn_rcpf(e + 1.0f);   // tanh(z)
    hbuf[tid] = (f16)hcur;                     // own slice only; no barrier
  }

  hstate[b * 256 + tid] = hcur;

  if (t0 + CT == 2048) {                       // fused fp32 classifier head
    hf[tid] = hcur;
    __syncthreads();
    int o = tid >> 4, s2 = tid & 15;
    const float* fw = fc_w + o * 256 + s2 * 16;
    float p = 0.f;
#pragma unroll
    for (int i = 0; i < 16; ++i) p += hf[s2 * 16 + i] * fw[i];
    prt2[o][s2] = p;
    __syncthreads();
    if (tid < 16) {
      float r = fc_b[tid];
#pragma unroll
      for (int s3 = 0; s3 < 16; ++s3) r += prt2[tid][s3];
      out[b * 16 + tid] = r;
    }
  }
}

// ---------------------------------------------------------------------------
extern "C" void kernel_launch(void* const* d_in, const int* in_sizes, int n_in,
                              void* d_out, int out_size, void* d_ws, size_t ws_size,
                              hipStream_t stream) {
  const float* x   = (const float*)d_in[0];
  const float* Wih = (const float*)d_in[1];
  const float* Whh = (const float*)d_in[2];
  const float* bh  = (const float*)d_in[3];
  const float* fcw = (const float*)d_in[4];
  const float* fcb = (const float*)d_in[5];
  float* out = (float*)d_out;

  char* ws = (char*)d_ws;
  uint4* Wfrag  = (uint4*)ws;                        // 128 KB
  uint4* Wc2    = (uint4*)(ws + (128 << 10));        // 128 KB
  float* hstate = (float*)(ws + (256 << 10));        // 256 KB
  f16*   xpb    = (f16*)(ws + (512 << 10));          // chunk buffer

  size_t avail = (ws_size > (size_t)(512 << 10)) ? ws_size - (size_t)(512 << 10) : 0;
  int CT = 2048;
  while (CT > 64 && (size_t)CT * 131072 > avail) CT >>= 1;

  int tpb = (CT >= 256) ? 4 : (CT >> 6);             // 64-step tiles per block
  int bpb = CT / (64 * tpb);                         // blocks per batch

  prep_kernel<<<64, 256, 0, stream>>>(Wih, Whh, Wfrag, Wc2);
  for (int t0 = 0; t0 < 2048; t0 += CT) {
    gemm_kernel<<<256 * bpb, 256, 0, stream>>>(x, Wfrag, xpb, t0, CT, tpb, bpb);
    rnn_kernel<<<256, 256, 0, stream>>>(xpb, Wc2, bh, fcw, fcb, hstate, out, t0, CT);
  }
}